// Round 10
// baseline (137.790 us; speedup 1.0000x reference)
//
#include <hip/hip_runtime.h>
#include <hip/hip_bf16.h>

#define B_ROWS 4096
#define NROWS  8192   // 2B
#define D      256
#define TILES  64     // NROWS / 128
#define NPAIRS 2080   // TILES*(TILES+1)/2

typedef __attribute__((ext_vector_type(4))) float floatx4;

// ---------------------------------------------------------------------------
// Kernel 1: normalize -> fp8 e4m3 z (2 MiB), exact fp32 pos, zero-inits.
// (proven R8/R9: absmax 0.0)
// ---------------------------------------------------------------------------
__global__ __launch_bounds__(256) void norm_pos_kernel(
    const float* __restrict__ xi, const float* __restrict__ xj,
    unsigned char* __restrict__ z, float* __restrict__ pos,
    float* __restrict__ rowsum, float* __restrict__ out,
    unsigned int* __restrict__ counter) {
    int gt = blockIdx.x * 256 + threadIdx.x;
    if (gt < NROWS) rowsum[gt] = 0.f;
    if (gt == 0) { out[0] = 0.f; counter[0] = 0u; }

    int p    = blockIdx.x * 4 + (threadIdx.x >> 6);
    int lane = threadIdx.x & 63;
    float4 v1 = ((const float4*)(xi + (size_t)p * D))[lane];
    float4 v2 = ((const float4*)(xj + (size_t)p * D))[lane];
    float ss1 = v1.x * v1.x + v1.y * v1.y + v1.z * v1.z + v1.w * v1.w;
    float ss2 = v2.x * v2.x + v2.y * v2.y + v2.z * v2.z + v2.w * v2.w;
#pragma unroll
    for (int off = 32; off > 0; off >>= 1) {
        ss1 += __shfl_xor(ss1, off);
        ss2 += __shfl_xor(ss2, off);
    }
    float sc1 = 1.0f / fmaxf(sqrtf(ss1), 1e-12f);
    float sc2 = 1.0f / fmaxf(sqrtf(ss2), 1e-12f);

    float n1x = v1.x * sc1, n1y = v1.y * sc1, n1z = v1.z * sc1, n1w = v1.w * sc1;
    float n2x = v2.x * sc2, n2y = v2.y * sc2, n2z = v2.z * sc2, n2w = v2.w * sc2;

    float dp = n1x * n2x + n1y * n2y + n1z * n2z + n1w * n2w;
#pragma unroll
    for (int off = 32; off > 0; off >>= 1) dp += __shfl_xor(dp, off);
    if (lane == 0) { pos[p] = dp; pos[p + B_ROWS] = dp; }

    int q1 = __builtin_amdgcn_cvt_pk_fp8_f32(n1x, n1y, 0, false);
    q1     = __builtin_amdgcn_cvt_pk_fp8_f32(n1z, n1w, q1, true);
    int q2 = __builtin_amdgcn_cvt_pk_fp8_f32(n2x, n2y, 0, false);
    q2     = __builtin_amdgcn_cvt_pk_fp8_f32(n2z, n2w, q2, true);
    ((int*)(z + (size_t)p * D))[lane]            = q1;
    ((int*)(z + (size_t)(p + B_ROWS) * D))[lane] = q2;
}

// ---------------------------------------------------------------------------
// Kernel 2: one block = one 128x128 tile pair (upper triangular). Whole-K
// one-shot LDS staging (fp8: A 32 KB + B 32 KB), ONE barrier, then a
// barrier-free K-loop of pure ds_read_b64 + mfma fp8. Wave tile 64x64.
// LDS layout (16B units): u(c16, row) = c16*128 + (row ^ ((c16&1)*16)).
//   staged write (lane: row=t>>2 (+64p), c16=(t&3)+4j): quads = row^{0,16}
//     pattern, 2 lanes/quad -> free.
//   frag read b64 (row=base+lm, c16=kk*2+(lg>>1), half=(lg&1)*8): lm spreads
//     16 quads, lg>>1 flips ^16, lg&1 shares unit halves -> 2-way, free.
//   global fetch: 4 consecutive lanes cover one 64B line -> coalesced.
// Diag tiles: predicate out row==col (no selfdot). Off-diag: mirror col-sums.
// ---------------------------------------------------------------------------
__global__ __launch_bounds__(256, 2) void sim_rowsum_kernel(
    const unsigned char* __restrict__ z, float* __restrict__ rowsum,
    const float* __restrict__ pos, unsigned int* __restrict__ counter,
    float* __restrict__ out) {
    __shared__ __align__(16) char Ab[32768];   // 32 KB
    __shared__ __align__(16) char Bb[32768];   // 32 KB
    __shared__ unsigned int done_s;
    __shared__ float sdata[4];

    const int tid  = threadIdx.x;
    const int lane = tid & 63;
    const int w    = tid >> 6;
    const int lm   = lane & 15;
    const int lg   = lane >> 4;

    // triangular decode (proven R3)
    int bid = blockIdx.x;
    int ti  = (int)((129.0 - sqrt(16641.0 - 8.0 * (double)bid)) * 0.5);
    while (ti > 0 && ti * TILES - ti * (ti - 1) / 2 > bid) ti--;
    while ((ti + 1) * TILES - (ti + 1) * ti / 2 <= bid) ti++;
    int tj = ti + (bid - (ti * TILES - ti * (ti - 1) / 2));
    const int m0 = ti * 128, n0 = tj * 128;
    const bool diag = (ti == tj);

    const int wr = (w & 1) * 64;
    const int wc = (w >> 1) * 64;

    // ---- one-shot staging: 128 rows x 256 B each for A and B ----
    {
        const int rb    = tid >> 2;      // 0..63
        const int spart = tid & 3;
        int4 pa[2][4], pb[2][4];
#pragma unroll
        for (int p = 0; p < 2; p++) {
            const int row = rb + p * 64;
            const unsigned char* pza = z + (size_t)(m0 + row) * D;
            const unsigned char* pzb = z + (size_t)(n0 + row) * D;
#pragma unroll
            for (int j = 0; j < 4; j++) {
                pa[p][j] = *(const int4*)(pza + spart * 16 + j * 64);
                pb[p][j] = *(const int4*)(pzb + spart * 16 + j * 64);
            }
        }
#pragma unroll
        for (int p = 0; p < 2; p++) {
            const int row = rb + p * 64;
#pragma unroll
            for (int j = 0; j < 4; j++) {
                const int c16 = spart + 4 * j;
                const int u   = c16 * 128 + (row ^ ((c16 & 1) * 16));
                *(int4*)(Ab + u * 16) = pa[p][j];
                *(int4*)(Bb + u * 16) = pb[p][j];
            }
        }
    }
    __syncthreads();

    // ---- barrier-free K-loop ----
    floatx4 acc[4][4];
#pragma unroll
    for (int mi = 0; mi < 4; mi++)
#pragma unroll
        for (int ni = 0; ni < 4; ni++) acc[mi][ni] = (floatx4){0.f, 0.f, 0.f, 0.f};

    const int h    = lg >> 1;       // c16 parity
    const int half = (lg & 1) * 8;  // byte half within 16B unit

#pragma unroll
    for (int kk = 0; kk < 8; kk++) {
        const int c16 = kk * 2 + h;
        const int x   = (c16 & 1) * 16;
        long long aF[4], bF[4];
#pragma unroll
        for (int mi = 0; mi < 4; mi++) {
            const int u = c16 * 128 + ((wr + mi * 16 + lm) ^ x);
            aF[mi] = *(const long long*)(Ab + u * 16 + half);
        }
#pragma unroll
        for (int ni = 0; ni < 4; ni++) {
            const int u = c16 * 128 + ((wc + ni * 16 + lm) ^ x);
            bF[ni] = *(const long long*)(Bb + u * 16 + half);
        }
#pragma unroll
        for (int mi = 0; mi < 4; mi++)
#pragma unroll
            for (int ni = 0; ni < 4; ni++)
                acc[mi][ni] = __builtin_amdgcn_mfma_f32_16x16x32_fp8_fp8(
                    aF[mi], bF[ni], acc[mi][ni], 0, 0, 0);
    }

    // ---- epilogue: exp(2*sim) -> row sums (+ mirror col sums) ----
    float rs[4][4], cs[4];
#pragma unroll
    for (int mi = 0; mi < 4; mi++)
#pragma unroll
        for (int r = 0; r < 4; r++) rs[mi][r] = 0.f;
#pragma unroll
    for (int ni = 0; ni < 4; ni++) cs[ni] = 0.f;

    if (diag) {
        const int rowb = m0 + wr + lg * 4;
#pragma unroll
        for (int mi = 0; mi < 4; mi++)
#pragma unroll
            for (int ni = 0; ni < 4; ni++) {
                const int gcol = n0 + wc + ni * 16 + lm;
#pragma unroll
                for (int r = 0; r < 4; r++) {
                    const int grow = rowb + mi * 16 + r;
                    float e = (grow == gcol) ? 0.f : __expf(2.0f * acc[mi][ni][r]);
                    rs[mi][r] += e;
                }
            }
    } else {
#pragma unroll
        for (int mi = 0; mi < 4; mi++)
#pragma unroll
            for (int ni = 0; ni < 4; ni++)
#pragma unroll
                for (int r = 0; r < 4; r++) {
                    float e = __expf(2.0f * acc[mi][ni][r]);
                    rs[mi][r] += e;
                    cs[ni]    += e;
                }
    }

#pragma unroll
    for (int mi = 0; mi < 4; mi++)
#pragma unroll
        for (int r = 0; r < 4; r++) {
            float v = rs[mi][r];
            v += __shfl_xor(v, 1); v += __shfl_xor(v, 2);
            v += __shfl_xor(v, 4); v += __shfl_xor(v, 8);
            if (lm == 0)
                atomicAdd(&rowsum[m0 + wr + mi * 16 + lg * 4 + r], v);
        }
    if (!diag) {
#pragma unroll
        for (int ni = 0; ni < 4; ni++) {
            float v = cs[ni];
            v += __shfl_xor(v, 16); v += __shfl_xor(v, 32);
            if (lane < 16)
                atomicAdd(&rowsum[n0 + wc + ni * 16 + lane], v);
        }
    }

    // ---- last-block-done: final loss ----
    __syncthreads();
    if (tid == 0) {
        __threadfence();
        done_s = atomicAdd(counter, 1u);
    }
    __syncthreads();
    if (done_s == (unsigned int)(NPAIRS - 1)) {
        __threadfence();
        float acc_l = 0.f;
#pragma unroll 4
        for (int r = tid; r < NROWS; r += 256) {
            float rsv = __hip_atomic_load(&rowsum[r], __ATOMIC_RELAXED,
                                          __HIP_MEMORY_SCOPE_AGENT);
            acc_l += -2.0f * pos[r] + logf(rsv);
        }
#pragma unroll
        for (int off = 32; off > 0; off >>= 1) acc_l += __shfl_xor(acc_l, off);
        if (lane == 0) sdata[w] = acc_l;
        __syncthreads();
        if (tid == 0)
            out[0] = (sdata[0] + sdata[1] + sdata[2] + sdata[3]) / (float)NROWS;
    }
}

// ---------------------------------------------------------------------------
extern "C" void kernel_launch(void* const* d_in, const int* in_sizes, int n_in,
                              void* d_out, int out_size, void* d_ws, size_t ws_size,
                              hipStream_t stream) {
    const float* xi = (const float*)d_in[0];
    const float* xj = (const float*)d_in[1];
    float* out      = (float*)d_out;

    char* ws         = (char*)d_ws;
    unsigned char* z = (unsigned char*)ws;                    // 2 MiB (fp8)
    float* rowsum    = (float*)(ws + (size_t)NROWS * D);      // 32 KiB
    float* pos       = rowsum + NROWS;                        // 32 KiB
    unsigned int* counter = (unsigned int*)(pos + NROWS);

    norm_pos_kernel<<<B_ROWS / 4, 256, 0, stream>>>(xi, xj, z, pos,
                                                    rowsum, out, counter);
    sim_rowsum_kernel<<<NPAIRS, 256, 0, stream>>>(z, rowsum, pos, counter, out);
}